// Round 12
// baseline (463.590 us; speedup 1.0000x reference)
//
#include <hip/hip_runtime.h>

typedef unsigned short u16;
typedef __bf16 bf16x8 __attribute__((ext_vector_type(8)));
typedef float f32x4 __attribute__((ext_vector_type(4)));
typedef unsigned int u32x4 __attribute__((ext_vector_type(4)));

#define MFMA16(a, b, c) __builtin_amdgcn_mfma_f32_16x16x32_bf16((a), (b), (c), 0, 0, 0)

#define NNODE 100000
#define EDGES 500000
#define NPAIR 1000000

__device__ __forceinline__ u16 bf16bits(float f) {
  __bf16 h = (__bf16)f;
  return __builtin_bit_cast(unsigned short, h);
}

// ---------------------------------------------------------------------------
// Prep: rewrite Wn1[256,256], Wn2[256,128], Ws1[256,256] (all [K][N] f32) into
// bf16 "fragment order": elem (n,k) -> (((n>>4)*8 + (k>>5))*64 + ((k>>3)&3)*16
// + (n&15))*8 + (k&7).  B-frag for (ntile, kstep) is then 64 consecutive 16B
// chunks (one per lane) -> conflict-free ds_read_b128 / coalesced staging.
// ws layout (u16): WnT1 @0 (65536), WnT2 @65536 (32768), WsT1 @98304 (65536),
// then bf16 H @163840 (12.8M u16) when ws_size permits.
// ---------------------------------------------------------------------------
__global__ void prep_weights(const float* __restrict__ Wn1,
                             const float* __restrict__ Wn2,
                             const float* __restrict__ Ws1,
                             u16* __restrict__ ws) {
  int gid = blockIdx.x * 256 + threadIdx.x;  // 163840 total
  const float* src;
  int ldn;
  u16* dst;
  int e;
  if (gid < 65536) {
    src = Wn1; ldn = 256; dst = ws; e = gid;
  } else if (gid < 98304) {
    src = Wn2; ldn = 128; dst = ws + 65536; e = gid - 65536;
  } else {
    src = Ws1; ldn = 256; dst = ws + 98304; e = gid - 98304;
  }
  int j = e & 7;
  int lane = (e >> 3) & 63;
  int s = (e >> 9) & 7;
  int nt = e >> 12;
  int n = (nt << 4) | (lane & 15);
  int k = (s << 5) | (((lane >> 4) & 3) << 3) | j;
  dst[e] = bf16bits(src[k * ldn + n]);
}

// ---------------------------------------------------------------------------
// Node MLP: H = relu(x@Wn1+bn1)@Wn2+bn2.  4 waves x 32 rows = 128 rows/block.
// Writes f32 H (required output) and optionally bf16 H copy for pair kernel.
// ---------------------------------------------------------------------------
__launch_bounds__(256, 2)
__global__ void node_kernel(const float* __restrict__ x,
                            const u16* __restrict__ WnT1,
                            const u16* __restrict__ WnT2,
                            const float* __restrict__ bn1,
                            const float* __restrict__ bn2,
                            float* __restrict__ Hout,
                            u16* __restrict__ Hb) {
  __shared__ __align__(16) u16 buf[32768];  // 64 KB
  const int tid = threadIdx.x;
  const int w = tid >> 6, l = tid & 63;
  const int lg = l >> 4, ll = l & 15;
  const int rowbase = blockIdx.x * 128 + w * 32;

  // A-frags from x (f32 -> bf16)
  bf16x8 af[2][8];
#pragma unroll
  for (int m = 0; m < 2; m++) {
    int r = rowbase + m * 16 + ll;
    if (r > NNODE - 1) r = NNODE - 1;
    const float* xp = x + (long)r * 256 + lg * 8;
#pragma unroll
    for (int c = 0; c < 8; c++) {
      f32x4 a0 = *(const f32x4*)(xp + c * 32);
      f32x4 a1 = *(const f32x4*)(xp + c * 32 + 4);
      bf16x8 d;
#pragma unroll
      for (int j = 0; j < 4; j++) {
        d[j] = (__bf16)a0[j];
        d[j + 4] = (__bf16)a1[j];
      }
      af[m][c] = d;
    }
  }

  // Layer 1: stage WnT1 in two 64KB halves, acc[2][16] (full 256 hidden cols)
  f32x4 acc[2][16];
#pragma unroll
  for (int nh = 0; nh < 2; nh++) {
    if (nh) __syncthreads();
    {
      const u32x4* src = (const u32x4*)(WnT1 + nh * 32768);
      u32x4* dstv = (u32x4*)buf;
#pragma unroll
      for (int i = 0; i < 16; i++) dstv[tid + i * 256] = src[tid + i * 256];
    }
    __syncthreads();
#pragma unroll
    for (int nt = 0; nt < 8; nt++) {
      int n = nh * 128 + nt * 16 + ll;
      float bv = bn1[n];
      f32x4 a0 = {bv, bv, bv, bv}, a1 = a0;
      const u16* bp = buf + nt * 4096 + l * 8;
#pragma unroll
      for (int s = 0; s < 8; s++) {
        bf16x8 bw = *(const bf16x8*)(bp + s * 512);
        a0 = MFMA16(af[0][s], bw, a0);
        a1 = MFMA16(af[1][s], bw, a1);
      }
      acc[0][nh * 8 + nt] = a0;
      acc[1][nh * 8 + nt] = a1;
    }
  }
  __syncthreads();  // everyone done reading WnT1 before h overwrites buf

  // relu -> bf16 h into per-wave LDS region, stored in A-frag order
  const int hbase = w * 8192;
#pragma unroll
  for (int m = 0; m < 2; m++) {
#pragma unroll
    for (int q = 0; q < 16; q++) {  // hidden-col tile (k = q*16 + ll)
      int s2 = q >> 1;
      int k3 = ((q & 1) << 1) | (ll >> 3);
      int j = ll & 7;
      f32x4 a = acc[m][q];
#pragma unroll
      for (int t = 0; t < 4; t++) {
        int lane2 = k3 * 16 + lg * 4 + t;  // row&15 = lg*4+t
        buf[hbase + ((m * 8 + s2) * 64 + lane2) * 8 + j] = bf16bits(fmaxf(a[t], 0.f));
      }
    }
  }
  // per-wave region only: no cross-wave barrier needed

  // Layer 2 A-frags from own h region (conflict-free: lane-contiguous 16B)
#pragma unroll
  for (int m = 0; m < 2; m++) {
#pragma unroll
    for (int s = 0; s < 8; s++) {
      af[m][s] = *(const bf16x8*)(buf + hbase + ((m * 8 + s) * 64 + l) * 8);
    }
  }

  // Layer 2: B-frags streamed from global (WnT2 is 64KB, L2-hot)
#pragma unroll
  for (int nt = 0; nt < 8; nt++) {
    int n = nt * 16 + ll;
    float bv = bn2[n];
    f32x4 a0 = {bv, bv, bv, bv}, a1 = a0;
    const u16* bp = WnT2 + nt * 4096 + l * 8;
#pragma unroll
    for (int s = 0; s < 8; s++) {
      bf16x8 bw = *(const bf16x8*)(bp + s * 512);
      a0 = MFMA16(af[0][s], bw, a0);
      a1 = MFMA16(af[1][s], bw, a1);
    }
#pragma unroll
    for (int t = 0; t < 4; t++) {
      int r0 = rowbase + lg * 4 + t;
      if (r0 < NNODE) {
        Hout[(long)r0 * 128 + n] = a0[t];
        if (Hb) Hb[(long)r0 * 128 + n] = bf16bits(a0[t]);
      }
      int r1 = rowbase + 16 + lg * 4 + t;
      if (r1 < NNODE) {
        Hout[(long)r1 * 128 + n] = a1[t];
        if (Hb) Hb[(long)r1 * 128 + n] = bf16bits(a1[t]);
      }
    }
  }
}

// ---------------------------------------------------------------------------
// Pair scorer v12 = r9's half-panel ping-pong kernel (proven correct, arch
// VGPR 120, no spill) + amdgpu_waves_per_eu(4,8).
// Occupancy law fitted over rounds 1-11: waves/SIMD = 512/(2 x VGPR_Count) —
// the compiler's unified-file arch/acc split charges ~2x arch per wave
// (64->4 waves, 120->2, 244->1).  wpe(4,8) caps TOTAL regs at 128/wave;
// r9's body = arch 120 + acc 8 = 128 exactly -> should fit without spill and
// make the 2nd block schedulable (16 waves x 128 = 2048 = pool).
// ---------------------------------------------------------------------------
template <bool BF16H>
__global__ __attribute__((amdgpu_waves_per_eu(4, 8)))
__launch_bounds__(512) void pair_kernel12(const void* __restrict__ Hsrc,
                                          const int* __restrict__ pos_u,
                                          const int* __restrict__ pos_v,
                                          const int* __restrict__ neg_u,
                                          const int* __restrict__ neg_v,
                                          const u16* __restrict__ WsT,
                                          const float* __restrict__ bs1,
                                          const float* __restrict__ Ws2,
                                          const float* __restrict__ bs2,
                                          float* __restrict__ out) {
  __shared__ __align__(16) u16 buf[32768];  // EXACTLY 64 KB: one panel half
  const int tid = threadIdx.x;
  const int w = tid >> 6, l = tid & 63;
  const int lg = l >> 4, ll = l & 15;
  const float b2 = bs2[0];

  // prologue: stage half 0
  {
    const u32x4* src = (const u32x4*)WsT;
    u32x4* dstv = (u32x4*)buf;
#pragma unroll
    for (int i = 0; i < 8; i++) dstv[tid + i * 512] = src[tid + i * 512];
  }
  __syncthreads();

  int res = 0;  // which half is resident in buf
  const int nchunks = (NPAIR + 255) / 256;  // 3907
  for (int chunk = blockIdx.x; chunk < nchunks; chunk += gridDim.x) {
    const int base = chunk * 256 + w * 32;

    // gather + build A-frags once per chunk: k<128 -> |hu-hv|, k>=128 -> hu*hv
    bf16x8 af[2][8];
#pragma unroll
    for (int m = 0; m < 2; m++) {
      int p = base + m * 16 + ll;
      int pc = (p < NPAIR) ? p : (NPAIR - 1);
      bool pos = pc < EDGES;
      int idx = pos ? pc : pc - EDGES;
      const int* ul = pos ? pos_u : neg_u;
      const int* vl = pos ? pos_v : neg_v;
      int u = ul[idx];
      int v = vl[idx];
      if constexpr (BF16H) {
        const u16* hu = (const u16*)Hsrc + (long)u * 128 + lg * 8;
        const u16* hv = (const u16*)Hsrc + (long)v * 128 + lg * 8;
#pragma unroll
        for (int c = 0; c < 4; c++) {
          bf16x8 a = *(const bf16x8*)(hu + c * 32);
          bf16x8 b = *(const bf16x8*)(hv + c * 32);
          bf16x8 d = a - b;
          u32x4 du = __builtin_bit_cast(u32x4, d) & 0x7FFF7FFFu;  // |.| pairwise
          af[m][c] = __builtin_bit_cast(bf16x8, du);
          af[m][c + 4] = a * b;
        }
      } else {
        const float* hu = (const float*)Hsrc + (long)u * 128 + lg * 8;
        const float* hv = (const float*)Hsrc + (long)v * 128 + lg * 8;
#pragma unroll
        for (int c = 0; c < 4; c++) {
          f32x4 a0 = *(const f32x4*)(hu + c * 32);
          f32x4 a1 = *(const f32x4*)(hu + c * 32 + 4);
          f32x4 b0 = *(const f32x4*)(hv + c * 32);
          f32x4 b1 = *(const f32x4*)(hv + c * 32 + 4);
          bf16x8 d, pr;
#pragma unroll
          for (int j = 0; j < 4; j++) {
            d[j] = (__bf16)__builtin_fabsf(a0[j] - b0[j]);
            d[j + 4] = (__bf16)__builtin_fabsf(a1[j] - b1[j]);
            pr[j] = (__bf16)(a0[j] * b0[j]);
            pr[j + 4] = (__bf16)(a1[j] * b1[j]);
          }
          af[m][c] = d;
          af[m][c + 4] = pr;
        }
      }
      __builtin_amdgcn_sched_barrier(0);  // bound in-flight gather registers
    }

    float lp[2][4] = {};

    // ---- compute over the RESIDENT half (nh = res) ----
#pragma unroll
    for (int nt = 0; nt < 8; nt++) {
      int n = res * 128 + nt * 16 + ll;
      float bv = bs1[n];
      f32x4 acc0 = {bv, bv, bv, bv}, acc1 = acc0;
      const u16* bp = buf + nt * 4096 + l * 8;
#pragma unroll
      for (int s = 0; s < 8; s++) {
        bf16x8 bw = *(const bf16x8*)(bp + s * 512);
        acc0 = MFMA16(af[0][s], bw, acc0);
        acc1 = MFMA16(af[1][s], bw, acc1);
      }
      float w2 = Ws2[n];
#pragma unroll
      for (int t = 0; t < 4; t++) {
        lp[0][t] += fmaxf(acc0[t], 0.f) * w2;
        lp[1][t] += fmaxf(acc1[t], 0.f) * w2;
      }
    }

    __syncthreads();  // all waves done reading resident half
    // ---- restage the OTHER half ----
    {
      const u32x4* src = (const u32x4*)(WsT + (res ^ 1) * 32768);
      u32x4* dstv = (u32x4*)buf;
#pragma unroll
      for (int i = 0; i < 8; i++) dstv[tid + i * 512] = src[tid + i * 512];
    }
    __syncthreads();  // staged half visible to all

    // ---- compute over the newly staged half (nh = res^1) ----
#pragma unroll
    for (int nt = 0; nt < 8; nt++) {
      int n = (res ^ 1) * 128 + nt * 16 + ll;
      float bv = bs1[n];
      f32x4 acc0 = {bv, bv, bv, bv}, acc1 = acc0;
      const u16* bp = buf + nt * 4096 + l * 8;
#pragma unroll
      for (int s = 0; s < 8; s++) {
        bf16x8 bw = *(const bf16x8*)(bp + s * 512);
        acc0 = MFMA16(af[0][s], bw, acc0);
        acc1 = MFMA16(af[1][s], bw, acc1);
      }
      float w2 = Ws2[n];
#pragma unroll
      for (int t = 0; t < 4; t++) {
        lp[0][t] += fmaxf(acc0[t], 0.f) * w2;
        lp[1][t] += fmaxf(acc1[t], 0.f) * w2;
      }
    }
    res ^= 1;  // the half we just staged stays resident for the next chunk

    // reduce across the 16 col-lanes; rows = lg*4 + t within each m-tile
#pragma unroll
    for (int m = 0; m < 2; m++) {
#pragma unroll
      for (int t = 0; t < 4; t++) {
        float v = lp[m][t];
        v += __shfl_xor(v, 1, 16);
        v += __shfl_xor(v, 2, 16);
        v += __shfl_xor(v, 4, 16);
        v += __shfl_xor(v, 8, 16);
        int p = base + m * 16 + lg * 4 + t;
        if (ll == 0 && p < NPAIR) out[p] = v + b2;
      }
    }
  }
}

extern "C" void kernel_launch(void* const* d_in, const int* in_sizes, int n_in,
                              void* d_out, int out_size, void* d_ws, size_t ws_size,
                              hipStream_t stream) {
  (void)in_sizes; (void)n_in; (void)out_size;
  const float* x = (const float*)d_in[0];
  const int* pos_u = (const int*)d_in[1];
  const int* pos_v = (const int*)d_in[2];
  const int* neg_u = (const int*)d_in[3];
  const int* neg_v = (const int*)d_in[4];
  const float* Wn1 = (const float*)d_in[5];
  const float* bn1 = (const float*)d_in[6];
  const float* Wn2 = (const float*)d_in[7];
  const float* bn2 = (const float*)d_in[8];
  const float* Ws1 = (const float*)d_in[9];
  const float* bs1 = (const float*)d_in[10];
  const float* Ws2 = (const float*)d_in[11];
  const float* bs2 = (const float*)d_in[12];
  float* out = (float*)d_out;
  u16* wsp = (u16*)d_ws;

  float* Hout = out + NPAIR;  // H output region: d_out[1e6 .. 1e6+12.8e6)
  const size_t need = 327680 + (size_t)NNODE * 128 * 2;  // bytes: weights + bf16 H
  const bool bf16h = ws_size >= need;
  u16* Hb = bf16h ? (wsp + 163840) : nullptr;

  prep_weights<<<640, 256, 0, stream>>>(Wn1, Wn2, Ws1, wsp);
  node_kernel<<<(NNODE + 127) / 128, 256, 0, stream>>>(x, wsp, wsp + 65536, bn1, bn2,
                                                       Hout, Hb);
  if (bf16h) {
    pair_kernel12<true><<<512, 512, 0, stream>>>(Hb, pos_u, pos_v, neg_u, neg_v,
                                                 wsp + 98304, bs1, Ws2, bs2, out);
  } else {
    pair_kernel12<false><<<512, 512, 0, stream>>>(Hout, pos_u, pos_v, neg_u, neg_v,
                                                  wsp + 98304, bs1, Ws2, bs2, out);
  }
}

// Round 13
// 256.805 us; speedup vs baseline: 1.8052x; 1.8052x over previous
//
#include <hip/hip_runtime.h>

typedef unsigned short u16;
typedef __bf16 bf16x8 __attribute__((ext_vector_type(8)));
typedef float f32x4 __attribute__((ext_vector_type(4)));
typedef unsigned int u32x4 __attribute__((ext_vector_type(4)));

#define MFMA16(a, b, c) __builtin_amdgcn_mfma_f32_16x16x32_bf16((a), (b), (c), 0, 0, 0)

#define NNODE 100000
#define EDGES 500000
#define NPAIR 1000000

__device__ __forceinline__ u16 bf16bits(float f) {
  __bf16 h = (__bf16)f;
  return __builtin_bit_cast(unsigned short, h);
}

// ---------------------------------------------------------------------------
// Prep: rewrite Wn1[256,256], Wn2[256,128], Ws1[256,256] (all [K][N] f32) into
// bf16 "fragment order": elem (n,k) -> (((n>>4)*8 + (k>>5))*64 + ((k>>3)&3)*16
// + (n&15))*8 + (k&7).  B-frag for (ntile, kstep) is then 64 consecutive 16B
// chunks (one per lane) -> conflict-free ds_read_b128 / coalesced staging.
// ws layout (u16): WnT1 @0 (65536), WnT2 @65536 (32768), WsT1 @98304 (65536),
// then bf16 H @163840 (12.8M u16) when ws_size permits.
// ---------------------------------------------------------------------------
__global__ void prep_weights(const float* __restrict__ Wn1,
                             const float* __restrict__ Wn2,
                             const float* __restrict__ Ws1,
                             u16* __restrict__ ws) {
  int gid = blockIdx.x * 256 + threadIdx.x;  // 163840 total
  const float* src;
  int ldn;
  u16* dst;
  int e;
  if (gid < 65536) {
    src = Wn1; ldn = 256; dst = ws; e = gid;
  } else if (gid < 98304) {
    src = Wn2; ldn = 128; dst = ws + 65536; e = gid - 65536;
  } else {
    src = Ws1; ldn = 256; dst = ws + 98304; e = gid - 98304;
  }
  int j = e & 7;
  int lane = (e >> 3) & 63;
  int s = (e >> 9) & 7;
  int nt = e >> 12;
  int n = (nt << 4) | (lane & 15);
  int k = (s << 5) | (((lane >> 4) & 3) << 3) | j;
  dst[e] = bf16bits(src[k * ldn + n]);
}

// ---------------------------------------------------------------------------
// Node MLP: H = relu(x@Wn1+bn1)@Wn2+bn2.  4 waves x 32 rows = 128 rows/block.
// Writes f32 H (required output) and optionally bf16 H copy for pair kernel.
// ---------------------------------------------------------------------------
__launch_bounds__(256, 2)
__global__ void node_kernel(const float* __restrict__ x,
                            const u16* __restrict__ WnT1,
                            const u16* __restrict__ WnT2,
                            const float* __restrict__ bn1,
                            const float* __restrict__ bn2,
                            float* __restrict__ Hout,
                            u16* __restrict__ Hb) {
  __shared__ __align__(16) u16 buf[32768];  // 64 KB
  const int tid = threadIdx.x;
  const int w = tid >> 6, l = tid & 63;
  const int lg = l >> 4, ll = l & 15;
  const int rowbase = blockIdx.x * 128 + w * 32;

  // A-frags from x (f32 -> bf16)
  bf16x8 af[2][8];
#pragma unroll
  for (int m = 0; m < 2; m++) {
    int r = rowbase + m * 16 + ll;
    if (r > NNODE - 1) r = NNODE - 1;
    const float* xp = x + (long)r * 256 + lg * 8;
#pragma unroll
    for (int c = 0; c < 8; c++) {
      f32x4 a0 = *(const f32x4*)(xp + c * 32);
      f32x4 a1 = *(const f32x4*)(xp + c * 32 + 4);
      bf16x8 d;
#pragma unroll
      for (int j = 0; j < 4; j++) {
        d[j] = (__bf16)a0[j];
        d[j + 4] = (__bf16)a1[j];
      }
      af[m][c] = d;
    }
  }

  // Layer 1: stage WnT1 in two 64KB halves, acc[2][16] (full 256 hidden cols)
  f32x4 acc[2][16];
#pragma unroll
  for (int nh = 0; nh < 2; nh++) {
    if (nh) __syncthreads();
    {
      const u32x4* src = (const u32x4*)(WnT1 + nh * 32768);
      u32x4* dstv = (u32x4*)buf;
#pragma unroll
      for (int i = 0; i < 16; i++) dstv[tid + i * 256] = src[tid + i * 256];
    }
    __syncthreads();
#pragma unroll
    for (int nt = 0; nt < 8; nt++) {
      int n = nh * 128 + nt * 16 + ll;
      float bv = bn1[n];
      f32x4 a0 = {bv, bv, bv, bv}, a1 = a0;
      const u16* bp = buf + nt * 4096 + l * 8;
#pragma unroll
      for (int s = 0; s < 8; s++) {
        bf16x8 bw = *(const bf16x8*)(bp + s * 512);
        a0 = MFMA16(af[0][s], bw, a0);
        a1 = MFMA16(af[1][s], bw, a1);
      }
      acc[0][nh * 8 + nt] = a0;
      acc[1][nh * 8 + nt] = a1;
    }
  }
  __syncthreads();  // everyone done reading WnT1 before h overwrites buf

  // relu -> bf16 h into per-wave LDS region, stored in A-frag order
  const int hbase = w * 8192;
#pragma unroll
  for (int m = 0; m < 2; m++) {
#pragma unroll
    for (int q = 0; q < 16; q++) {  // hidden-col tile (k = q*16 + ll)
      int s2 = q >> 1;
      int k3 = ((q & 1) << 1) | (ll >> 3);
      int j = ll & 7;
      f32x4 a = acc[m][q];
#pragma unroll
      for (int t = 0; t < 4; t++) {
        int lane2 = k3 * 16 + lg * 4 + t;  // row&15 = lg*4+t
        buf[hbase + ((m * 8 + s2) * 64 + lane2) * 8 + j] = bf16bits(fmaxf(a[t], 0.f));
      }
    }
  }
  // per-wave region only: no cross-wave barrier needed

  // Layer 2 A-frags from own h region (conflict-free: lane-contiguous 16B)
#pragma unroll
  for (int m = 0; m < 2; m++) {
#pragma unroll
    for (int s = 0; s < 8; s++) {
      af[m][s] = *(const bf16x8*)(buf + hbase + ((m * 8 + s) * 64 + l) * 8);
    }
  }

  // Layer 2: B-frags streamed from global (WnT2 is 64KB, L2-hot)
#pragma unroll
  for (int nt = 0; nt < 8; nt++) {
    int n = nt * 16 + ll;
    float bv = bn2[n];
    f32x4 a0 = {bv, bv, bv, bv}, a1 = a0;
    const u16* bp = WnT2 + nt * 4096 + l * 8;
#pragma unroll
    for (int s = 0; s < 8; s++) {
      bf16x8 bw = *(const bf16x8*)(bp + s * 512);
      a0 = MFMA16(af[0][s], bw, a0);
      a1 = MFMA16(af[1][s], bw, a1);
    }
#pragma unroll
    for (int t = 0; t < 4; t++) {
      int r0 = rowbase + lg * 4 + t;
      if (r0 < NNODE) {
        Hout[(long)r0 * 128 + n] = a0[t];
        if (Hb) Hb[(long)r0 * 128 + n] = bf16bits(a0[t]);
      }
      int r1 = rowbase + 16 + lg * 4 + t;
      if (r1 < NNODE) {
        Hout[(long)r1 * 128 + n] = a1[t];
        if (Hb) Hb[(long)r1 * 128 + n] = bf16bits(a1[t]);
      }
    }
  }
}

// ---------------------------------------------------------------------------
// Pair scorer v13 = r7 (best measured: 210 us, full 128KB panel, 512 thr,
// 2 waves/SIMD, zero main-loop barriers) + within-wave ILP fixes:
//  (a) UNFENCED gather: all 32 H-loads in flight at once (one latency
//      exposure; the r5 fences serialized two batches).  Mw=32 pressure is
//      safe unfenced (r1: same body, 112 VGPR, no spill).
//  (b) index prefetch: next tile's 4 edge indices loaded during the current
//      tile's MFMA loop -> removes idx->gather serial dependency.
//  (c) s_setprio(1) around the MFMA loop (waves are out-of-phase).
// Occupancy law (r1-r12): HW charges ~2x arch VGPR/wave; this body (~125)
// -> 2 waves/SIMD; arch<=64 needs Mw=16 which doubles LDS traffic -> dead end.
// ---------------------------------------------------------------------------
template <bool BF16H>
__launch_bounds__(512, 1)
__global__ void pair_kernel13(const void* __restrict__ Hsrc,
                              const int* __restrict__ pos_u,
                              const int* __restrict__ pos_v,
                              const int* __restrict__ neg_u,
                              const int* __restrict__ neg_v,
                              const u16* __restrict__ WsT,
                              const float* __restrict__ bs1,
                              const float* __restrict__ Ws2,
                              const float* __restrict__ bs2,
                              float* __restrict__ out) {
  __shared__ __align__(16) u16 buf[65536];  // 128 KB: full Ws1 panel
  __shared__ float cvec[512];               // [0..256) = bs1, [256..512) = Ws2
  const int tid = threadIdx.x;
  {
    const u32x4* src = (const u32x4*)WsT;
    u32x4* dstv = (u32x4*)buf;
#pragma unroll
    for (int i = 0; i < 16; i++) dstv[tid + i * 512] = src[tid + i * 512];
    cvec[tid] = (tid < 256) ? bs1[tid] : Ws2[tid - 256];
  }
  __syncthreads();  // the only barrier

  const int w = tid >> 6, l = tid & 63;
  const int lg = l >> 4, ll = l & 15;
  const float b2 = bs2[0];

  const int wstride = gridDim.x * 8;
  const int wid0 = blockIdx.x * 8 + w;

  // index prefetch for the first tile
  int un[2], vn[2];
#pragma unroll
  for (int m = 0; m < 2; m++) {
    int p = wid0 * 32 + m * 16 + ll;
    bool pos = p < EDGES;
    int idx = pos ? p : p - EDGES;
    un[m] = pos ? pos_u[idx] : neg_u[idx];
    vn[m] = pos ? pos_v[idx] : neg_v[idx];
  }

  // 1e6 / 32 = 31250 tiles exactly
  for (int tile = wid0; tile < 31250; tile += wstride) {
    const int base = tile * 32;
    const int u0 = un[0], v0 = vn[0], u1 = un[1], v1 = vn[1];

    // gather + build A-frags (unfenced: all loads issue together)
    bf16x8 af[2][8];
#pragma unroll
    for (int m = 0; m < 2; m++) {
      const int uu = m ? u1 : u0;
      const int vv = m ? v1 : v0;
      if constexpr (BF16H) {
        const u16* hu = (const u16*)Hsrc + (long)uu * 128 + lg * 8;
        const u16* hv = (const u16*)Hsrc + (long)vv * 128 + lg * 8;
#pragma unroll
        for (int c = 0; c < 4; c++) {
          bf16x8 a = *(const bf16x8*)(hu + c * 32);
          bf16x8 b = *(const bf16x8*)(hv + c * 32);
          bf16x8 d = a - b;
          u32x4 du = __builtin_bit_cast(u32x4, d) & 0x7FFF7FFFu;  // |.| pairwise
          af[m][c] = __builtin_bit_cast(bf16x8, du);
          af[m][c + 4] = a * b;
        }
      } else {
        const float* hu = (const float*)Hsrc + (long)uu * 128 + lg * 8;
        const float* hv = (const float*)Hsrc + (long)vv * 128 + lg * 8;
#pragma unroll
        for (int c = 0; c < 4; c++) {
          f32x4 a0 = *(const f32x4*)(hu + c * 32);
          f32x4 a1 = *(const f32x4*)(hu + c * 32 + 4);
          f32x4 b0 = *(const f32x4*)(hv + c * 32);
          f32x4 b1 = *(const f32x4*)(hv + c * 32 + 4);
          bf16x8 d, pr;
#pragma unroll
          for (int j = 0; j < 4; j++) {
            d[j] = (__bf16)__builtin_fabsf(a0[j] - b0[j]);
            d[j + 4] = (__bf16)__builtin_fabsf(a1[j] - b1[j]);
            pr[j] = (__bf16)(a0[j] * b0[j]);
            pr[j + 4] = (__bf16)(a1[j] * b1[j]);
          }
          af[m][c] = d;
          af[m][c + 4] = pr;
        }
      }
    }

    // prefetch indices for the next tile (latency hides under MFMA loop)
    {
      int tnext = tile + wstride;
      int pbase = (tnext < 31250 ? tnext : wid0) * 32;
#pragma unroll
      for (int m = 0; m < 2; m++) {
        int p = pbase + m * 16 + ll;
        bool pos = p < EDGES;
        int idx = pos ? p : p - EDGES;
        un[m] = pos ? pos_u[idx] : neg_u[idx];
        vn[m] = pos ? pos_v[idx] : neg_v[idx];
      }
    }

    float lp[2][4] = {};
    __builtin_amdgcn_s_setprio(1);
#pragma unroll
    for (int nt = 0; nt < 16; nt++) {
      float bv = cvec[nt * 16 + ll];
      f32x4 acc0 = {bv, bv, bv, bv}, acc1 = acc0;
      const u16* bp = buf + nt * 4096 + l * 8;
#pragma unroll
      for (int s = 0; s < 8; s++) {
        bf16x8 bw = *(const bf16x8*)(bp + s * 512);
        acc0 = MFMA16(af[0][s], bw, acc0);
        acc1 = MFMA16(af[1][s], bw, acc1);
      }
      float w2 = cvec[256 + nt * 16 + ll];
#pragma unroll
      for (int t = 0; t < 4; t++) {
        lp[0][t] += fmaxf(acc0[t], 0.f) * w2;
        lp[1][t] += fmaxf(acc1[t], 0.f) * w2;
      }
    }
    __builtin_amdgcn_s_setprio(0);

    // reduce across the 16 col-lanes; rows = lg*4 + t within each m-tile
#pragma unroll
    for (int m = 0; m < 2; m++) {
#pragma unroll
      for (int t = 0; t < 4; t++) {
        float v = lp[m][t];
        v += __shfl_xor(v, 1, 16);
        v += __shfl_xor(v, 2, 16);
        v += __shfl_xor(v, 4, 16);
        v += __shfl_xor(v, 8, 16);
        if (ll == 0) out[base + m * 16 + lg * 4 + t] = v + b2;
      }
    }
  }
}

extern "C" void kernel_launch(void* const* d_in, const int* in_sizes, int n_in,
                              void* d_out, int out_size, void* d_ws, size_t ws_size,
                              hipStream_t stream) {
  (void)in_sizes; (void)n_in; (void)out_size;
  const float* x = (const float*)d_in[0];
  const int* pos_u = (const int*)d_in[1];
  const int* pos_v = (const int*)d_in[2];
  const int* neg_u = (const int*)d_in[3];
  const int* neg_v = (const int*)d_in[4];
  const float* Wn1 = (const float*)d_in[5];
  const float* bn1 = (const float*)d_in[6];
  const float* Wn2 = (const float*)d_in[7];
  const float* bn2 = (const float*)d_in[8];
  const float* Ws1 = (const float*)d_in[9];
  const float* bs1 = (const float*)d_in[10];
  const float* Ws2 = (const float*)d_in[11];
  const float* bs2 = (const float*)d_in[12];
  float* out = (float*)d_out;
  u16* wsp = (u16*)d_ws;

  float* Hout = out + NPAIR;  // H output region: d_out[1e6 .. 1e6+12.8e6)
  const size_t need = 327680 + (size_t)NNODE * 128 * 2;  // bytes: weights + bf16 H
  const bool bf16h = ws_size >= need;
  u16* Hb = bf16h ? (wsp + 163840) : nullptr;

  prep_weights<<<640, 256, 0, stream>>>(Wn1, Wn2, Ws1, wsp);
  node_kernel<<<(NNODE + 127) / 128, 256, 0, stream>>>(x, wsp, wsp + 65536, bn1, bn2,
                                                       Hout, Hb);
  if (bf16h) {
    pair_kernel13<true><<<256, 512, 0, stream>>>(Hb, pos_u, pos_v, neg_u, neg_v,
                                                 wsp + 98304, bs1, Ws2, bs2, out);
  } else {
    pair_kernel13<false><<<256, 512, 0, stream>>>(Hout, pos_u, pos_v, neg_u, neg_v,
                                                  wsp + 98304, bs1, Ws2, bs2, out);
  }
}

// Round 15
// 254.531 us; speedup vs baseline: 1.8214x; 1.0089x over previous
//
#include <hip/hip_runtime.h>

typedef unsigned short u16;
typedef __bf16 bf16x8 __attribute__((ext_vector_type(8)));
typedef float f32x4 __attribute__((ext_vector_type(4)));
typedef unsigned int u32x4 __attribute__((ext_vector_type(4)));

#define MFMA16(a, b, c) __builtin_amdgcn_mfma_f32_16x16x32_bf16((a), (b), (c), 0, 0, 0)

#define NNODE 100000
#define EDGES 500000
#define NPAIR 1000000

__device__ __forceinline__ u16 bf16bits(float f) {
  __bf16 h = (__bf16)f;
  return __builtin_bit_cast(unsigned short, h);
}

// ---------------------------------------------------------------------------
// Prep: rewrite Wn1[256,256], Wn2[256,128], Ws1[256,256] (all [K][N] f32) into
// bf16 "fragment order": elem (n,k) -> (((n>>4)*8 + (k>>5))*64 + ((k>>3)&3)*16
// + (n&15))*8 + (k&7).  B-frag for (ntile, kstep) is then 64 consecutive 16B
// chunks (one per lane) -> conflict-free ds_read_b128 / coalesced staging.
// ws layout (u16): WnT1 @0 (65536), WnT2 @65536 (32768), WsT1 @98304 (65536),
// then bf16 H @163840 (12.8M u16) when ws_size permits.
// ---------------------------------------------------------------------------
__global__ void prep_weights(const float* __restrict__ Wn1,
                             const float* __restrict__ Wn2,
                             const float* __restrict__ Ws1,
                             u16* __restrict__ ws) {
  int gid = blockIdx.x * 256 + threadIdx.x;  // 163840 total
  const float* src;
  int ldn;
  u16* dst;
  int e;
  if (gid < 65536) {
    src = Wn1; ldn = 256; dst = ws; e = gid;
  } else if (gid < 98304) {
    src = Wn2; ldn = 128; dst = ws + 65536; e = gid - 65536;
  } else {
    src = Ws1; ldn = 256; dst = ws + 98304; e = gid - 98304;
  }
  int j = e & 7;
  int lane = (e >> 3) & 63;
  int s = (e >> 9) & 7;
  int nt = e >> 12;
  int n = (nt << 4) | (lane & 15);
  int k = (s << 5) | (((lane >> 4) & 3) << 3) | j;
  dst[e] = bf16bits(src[k * ldn + n]);
}

// ---------------------------------------------------------------------------
// Node MLP: H = relu(x@Wn1+bn1)@Wn2+bn2.  4 waves x 32 rows = 128 rows/block.
// Writes f32 H (required output) and optionally bf16 H copy for pair kernel.
// ---------------------------------------------------------------------------
__launch_bounds__(256, 2)
__global__ void node_kernel(const float* __restrict__ x,
                            const u16* __restrict__ WnT1,
                            const u16* __restrict__ WnT2,
                            const float* __restrict__ bn1,
                            const float* __restrict__ bn2,
                            float* __restrict__ Hout,
                            u16* __restrict__ Hb) {
  __shared__ __align__(16) u16 buf[32768];  // 64 KB
  const int tid = threadIdx.x;
  const int w = tid >> 6, l = tid & 63;
  const int lg = l >> 4, ll = l & 15;
  const int rowbase = blockIdx.x * 128 + w * 32;

  // A-frags from x (f32 -> bf16)
  bf16x8 af[2][8];
#pragma unroll
  for (int m = 0; m < 2; m++) {
    int r = rowbase + m * 16 + ll;
    if (r > NNODE - 1) r = NNODE - 1;
    const float* xp = x + (long)r * 256 + lg * 8;
#pragma unroll
    for (int c = 0; c < 8; c++) {
      f32x4 a0 = *(const f32x4*)(xp + c * 32);
      f32x4 a1 = *(const f32x4*)(xp + c * 32 + 4);
      bf16x8 d;
#pragma unroll
      for (int j = 0; j < 4; j++) {
        d[j] = (__bf16)a0[j];
        d[j + 4] = (__bf16)a1[j];
      }
      af[m][c] = d;
    }
  }

  // Layer 1: stage WnT1 in two 64KB halves, acc[2][16] (full 256 hidden cols)
  f32x4 acc[2][16];
#pragma unroll
  for (int nh = 0; nh < 2; nh++) {
    if (nh) __syncthreads();
    {
      const u32x4* src = (const u32x4*)(WnT1 + nh * 32768);
      u32x4* dstv = (u32x4*)buf;
#pragma unroll
      for (int i = 0; i < 16; i++) dstv[tid + i * 256] = src[tid + i * 256];
    }
    __syncthreads();
#pragma unroll
    for (int nt = 0; nt < 8; nt++) {
      int n = nh * 128 + nt * 16 + ll;
      float bv = bn1[n];
      f32x4 a0 = {bv, bv, bv, bv}, a1 = a0;
      const u16* bp = buf + nt * 4096 + l * 8;
#pragma unroll
      for (int s = 0; s < 8; s++) {
        bf16x8 bw = *(const bf16x8*)(bp + s * 512);
        a0 = MFMA16(af[0][s], bw, a0);
        a1 = MFMA16(af[1][s], bw, a1);
      }
      acc[0][nh * 8 + nt] = a0;
      acc[1][nh * 8 + nt] = a1;
    }
  }
  __syncthreads();  // everyone done reading WnT1 before h overwrites buf

  // relu -> bf16 h into per-wave LDS region, stored in A-frag order
  const int hbase = w * 8192;
#pragma unroll
  for (int m = 0; m < 2; m++) {
#pragma unroll
    for (int q = 0; q < 16; q++) {  // hidden-col tile (k = q*16 + ll)
      int s2 = q >> 1;
      int k3 = ((q & 1) << 1) | (ll >> 3);
      int j = ll & 7;
      f32x4 a = acc[m][q];
#pragma unroll
      for (int t = 0; t < 4; t++) {
        int lane2 = k3 * 16 + lg * 4 + t;  // row&15 = lg*4+t
        buf[hbase + ((m * 8 + s2) * 64 + lane2) * 8 + j] = bf16bits(fmaxf(a[t], 0.f));
      }
    }
  }
  // per-wave region only: no cross-wave barrier needed

  // Layer 2 A-frags from own h region (conflict-free: lane-contiguous 16B)
#pragma unroll
  for (int m = 0; m < 2; m++) {
#pragma unroll
    for (int s = 0; s < 8; s++) {
      af[m][s] = *(const bf16x8*)(buf + hbase + ((m * 8 + s) * 64 + l) * 8);
    }
  }

  // Layer 2: B-frags streamed from global (WnT2 is 64KB, L2-hot)
#pragma unroll
  for (int nt = 0; nt < 8; nt++) {
    int n = nt * 16 + ll;
    float bv = bn2[n];
    f32x4 a0 = {bv, bv, bv, bv}, a1 = a0;
    const u16* bp = WnT2 + nt * 4096 + l * 8;
#pragma unroll
    for (int s = 0; s < 8; s++) {
      bf16x8 bw = *(const bf16x8*)(bp + s * 512);
      a0 = MFMA16(af[0][s], bw, a0);
      a1 = MFMA16(af[1][s], bw, a1);
    }
#pragma unroll
    for (int t = 0; t < 4; t++) {
      int r0 = rowbase + lg * 4 + t;
      if (r0 < NNODE) {
        Hout[(long)r0 * 128 + n] = a0[t];
        if (Hb) Hb[(long)r0 * 128 + n] = bf16bits(a0[t]);
      }
      int r1 = rowbase + 16 + lg * 4 + t;
      if (r1 < NNODE) {
        Hout[(long)r1 * 128 + n] = a1[t];
        if (Hb) Hb[(long)r1 * 128 + n] = bf16bits(a1[t]);
      }
    }
  }
}

// ---------------------------------------------------------------------------
// Pair scorer v15 = r13 (best measured: 204 us pair).  Full 128KB panel in
// LDS staged once, 512 thr / 8 waves, zero main-loop barriers, Mw=32/wave,
// unfenced gather + next-tile index prefetch + setprio around MFMA loop.
// Constraint web (measured r1-r14): HW charges ~2x arch VGPR per wave ->
// ~125-VGPR body pinned at 2 waves/SIMD; occupancy escapes all fail
// (bigger blocks spill, N-split duplicates VALU, arch<=64 co-residency
// spills, AGPR-asm offload breaks MFMA hazard insertion).  At 2 waves/SIMD
// the pipe floors (LDS 78us + VALU 65us + MFMA 63us) sum to ~206us ~= the
// measured 204: practical ceiling of this structure.
// ---------------------------------------------------------------------------
template <bool BF16H>
__launch_bounds__(512, 1)
__global__ void pair_kernel15(const void* __restrict__ Hsrc,
                              const int* __restrict__ pos_u,
                              const int* __restrict__ pos_v,
                              const int* __restrict__ neg_u,
                              const int* __restrict__ neg_v,
                              const u16* __restrict__ WsT,
                              const float* __restrict__ bs1,
                              const float* __restrict__ Ws2,
                              const float* __restrict__ bs2,
                              float* __restrict__ out) {
  __shared__ __align__(16) u16 buf[65536];  // 128 KB: full Ws1 panel
  __shared__ float cvec[512];               // [0..256) = bs1, [256..512) = Ws2
  const int tid = threadIdx.x;
  {
    const u32x4* src = (const u32x4*)WsT;
    u32x4* dstv = (u32x4*)buf;
#pragma unroll
    for (int i = 0; i < 16; i++) dstv[tid + i * 512] = src[tid + i * 512];
    cvec[tid] = (tid < 256) ? bs1[tid] : Ws2[tid - 256];
  }
  __syncthreads();  // the only barrier

  const int w = tid >> 6, l = tid & 63;
  const int lg = l >> 4, ll = l & 15;
  const float b2 = bs2[0];

  const int wstride = gridDim.x * 8;
  const int wid0 = blockIdx.x * 8 + w;

  // index prefetch for the first tile
  int un[2], vn[2];
#pragma unroll
  for (int m = 0; m < 2; m++) {
    int p = wid0 * 32 + m * 16 + ll;
    bool pos = p < EDGES;
    int idx = pos ? p : p - EDGES;
    un[m] = pos ? pos_u[idx] : neg_u[idx];
    vn[m] = pos ? pos_v[idx] : neg_v[idx];
  }

  // 1e6 / 32 = 31250 tiles exactly
  for (int tile = wid0; tile < 31250; tile += wstride) {
    const int base = tile * 32;
    const int u0 = un[0], v0 = vn[0], u1 = un[1], v1 = vn[1];

    // gather + build A-frags (unfenced: all loads issue together)
    bf16x8 af[2][8];
#pragma unroll
    for (int m = 0; m < 2; m++) {
      const int uu = m ? u1 : u0;
      const int vv = m ? v1 : v0;
      if constexpr (BF16H) {
        const u16* hu = (const u16*)Hsrc + (long)uu * 128 + lg * 8;
        const u16* hv = (const u16*)Hsrc + (long)vv * 128 + lg * 8;
#pragma unroll
        for (int c = 0; c < 4; c++) {
          bf16x8 a = *(const bf16x8*)(hu + c * 32);
          bf16x8 b = *(const bf16x8*)(hv + c * 32);
          bf16x8 d = a - b;
          u32x4 du = __builtin_bit_cast(u32x4, d) & 0x7FFF7FFFu;  // |.| pairwise
          af[m][c] = __builtin_bit_cast(bf16x8, du);
          af[m][c + 4] = a * b;
        }
      } else {
        const float* hu = (const float*)Hsrc + (long)uu * 128 + lg * 8;
        const float* hv = (const float*)Hsrc + (long)vv * 128 + lg * 8;
#pragma unroll
        for (int c = 0; c < 4; c++) {
          f32x4 a0 = *(const f32x4*)(hu + c * 32);
          f32x4 a1 = *(const f32x4*)(hu + c * 32 + 4);
          f32x4 b0 = *(const f32x4*)(hv + c * 32);
          f32x4 b1 = *(const f32x4*)(hv + c * 32 + 4);
          bf16x8 d, pr;
#pragma unroll
          for (int j = 0; j < 4; j++) {
            d[j] = (__bf16)__builtin_fabsf(a0[j] - b0[j]);
            d[j + 4] = (__bf16)__builtin_fabsf(a1[j] - b1[j]);
            pr[j] = (__bf16)(a0[j] * b0[j]);
            pr[j + 4] = (__bf16)(a1[j] * b1[j]);
          }
          af[m][c] = d;
          af[m][c + 4] = pr;
        }
      }
    }

    // prefetch indices for the next tile (latency hides under MFMA loop)
    {
      int tnext = tile + wstride;
      int pbase = (tnext < 31250 ? tnext : wid0) * 32;
#pragma unroll
      for (int m = 0; m < 2; m++) {
        int p = pbase + m * 16 + ll;
        bool pos = p < EDGES;
        int idx = pos ? p : p - EDGES;
        un[m] = pos ? pos_u[idx] : neg_u[idx];
        vn[m] = pos ? pos_v[idx] : neg_v[idx];
      }
    }

    float lp[2][4] = {};
    __builtin_amdgcn_s_setprio(1);
#pragma unroll
    for (int nt = 0; nt < 16; nt++) {
      float bv = cvec[nt * 16 + ll];
      f32x4 acc0 = {bv, bv, bv, bv}, acc1 = acc0;
      const u16* bp = buf + nt * 4096 + l * 8;
#pragma unroll
      for (int s = 0; s < 8; s++) {
        bf16x8 bw = *(const bf16x8*)(bp + s * 512);
        acc0 = MFMA16(af[0][s], bw, acc0);
        acc1 = MFMA16(af[1][s], bw, acc1);
      }
      float w2 = cvec[256 + nt * 16 + ll];
#pragma unroll
      for (int t = 0; t < 4; t++) {
        lp[0][t] += fmaxf(acc0[t], 0.f) * w2;
        lp[1][t] += fmaxf(acc1[t], 0.f) * w2;
      }
    }
    __builtin_amdgcn_s_setprio(0);

    // reduce across the 16 col-lanes; rows = lg*4 + t within each m-tile
#pragma unroll
    for (int m = 0; m < 2; m++) {
#pragma unroll
      for (int t = 0; t < 4; t++) {
        float v = lp[m][t];
        v += __shfl_xor(v, 1, 16);
        v += __shfl_xor(v, 2, 16);
        v += __shfl_xor(v, 4, 16);
        v += __shfl_xor(v, 8, 16);
        if (ll == 0) out[base + m * 16 + lg * 4 + t] = v + b2;
      }
    }
  }
}

extern "C" void kernel_launch(void* const* d_in, const int* in_sizes, int n_in,
                              void* d_out, int out_size, void* d_ws, size_t ws_size,
                              hipStream_t stream) {
  (void)in_sizes; (void)n_in; (void)out_size;
  const float* x = (const float*)d_in[0];
  const int* pos_u = (const int*)d_in[1];
  const int* pos_v = (const int*)d_in[2];
  const int* neg_u = (const int*)d_in[3];
  const int* neg_v = (const int*)d_in[4];
  const float* Wn1 = (const float*)d_in[5];
  const float* bn1 = (const float*)d_in[6];
  const float* Wn2 = (const float*)d_in[7];
  const float* bn2 = (const float*)d_in[8];
  const float* Ws1 = (const float*)d_in[9];
  const float* bs1 = (const float*)d_in[10];
  const float* Ws2 = (const float*)d_in[11];
  const float* bs2 = (const float*)d_in[12];
  float* out = (float*)d_out;
  u16* wsp = (u16*)d_ws;

  float* Hout = out + NPAIR;  // H output region: d_out[1e6 .. 1e6+12.8e6)
  const size_t need = 327680 + (size_t)NNODE * 128 * 2;  // bytes: weights + bf16 H
  const bool bf16h = ws_size >= need;
  u16* Hb = bf16h ? (wsp + 163840) : nullptr;

  prep_weights<<<640, 256, 0, stream>>>(Wn1, Wn2, Ws1, wsp);
  node_kernel<<<(NNODE + 127) / 128, 256, 0, stream>>>(x, wsp, wsp + 65536, bn1, bn2,
                                                       Hout, Hb);
  if (bf16h) {
    pair_kernel15<true><<<256, 512, 0, stream>>>(Hb, pos_u, pos_v, neg_u, neg_v,
                                                 wsp + 98304, bs1, Ws2, bs2, out);
  } else {
    pair_kernel15<false><<<256, 512, 0, stream>>>(Hout, pos_u, pos_v, neg_u, neg_v,
                                                  wsp + 98304, bs1, Ws2, bs2, out);
  }
}